// Round 13
// baseline (168.826 us; speedup 1.0000x reference)
//
#include <hip/hip_runtime.h>
#include <stdint.h>

#define HIDDEN 1024
#define SEQ 4096
#define BATCH 4
#define HEADS 16
#define HDIM 64
#define M_TOT (BATCH * SEQ)   // 16384
#define NCH 4                 // split-S chunks for kv reduction
#define NT 32                 // K-steps of 32 in projection GEMMs

typedef __bf16 bf16x8 __attribute__((ext_vector_type(8)));
typedef float f32x4 __attribute__((ext_vector_type(4)));
typedef unsigned short u16x8 __attribute__((ext_vector_type(8)));

static __device__ __forceinline__ unsigned short f2bf(float f) {
  union { float f; uint32_t u; } v; v.f = f;
  uint32_t u = v.u;
  uint32_t r = (u + 0x7fffu + ((u >> 16) & 1u)) >> 16;
  return (unsigned short)r;
}
static __device__ __forceinline__ void load_lds16(const void* g, void* l) {
  __builtin_amdgcn_global_load_lds(
      (__attribute__((address_space(1))) void*)(g),
      (__attribute__((address_space(3))) void*)(l), 16, 0, 0);
}

// ---------------- fused prep kernel ----------------
__global__ __launch_bounds__(256) void prep_k(
    const float* __restrict__ x, unsigned short* __restrict__ xb,
    const float* __restrict__ Wk, const float* __restrict__ Wv,
    const float* __restrict__ Wq,
    unsigned short* __restrict__ Bt, unsigned short* __restrict__ Wqt,
    const float* __restrict__ bk, const float* __restrict__ bv,
    float* __restrict__ bkv,
    const float* __restrict__ mask, float* __restrict__ norm) {
  const int bid = blockIdx.x;
  const int tid = threadIdx.x;
  __shared__ float ts[64][65];
  if (bid < 8192) {
    int idx = bid * 256 + tid;
    const float4* xv = (const float4*)x;
    float4 a = xv[(size_t)idx * 2];
    float4 b = xv[(size_t)idx * 2 + 1];
    u16x8 o;
    o[0] = f2bf(a.x); o[1] = f2bf(a.y); o[2] = f2bf(a.z); o[3] = f2bf(a.w);
    o[4] = f2bf(b.x); o[5] = f2bf(b.y); o[6] = f2bf(b.z); o[7] = f2bf(b.w);
    *(u16x8*)(xb + (size_t)idx * 8) = o;
  } else if (bid < 8960) {
    int idx = bid - 8192;
    int z = idx >> 8, rem = idx & 255;
    const float* W = (z == 0) ? Wk : (z == 1) ? Wv : Wq;
    unsigned short* out = (z == 2) ? Wqt : (Bt + (size_t)z * HIDDEN * HIDDEN);
    int n0 = (rem & 15) * 64, k0 = (rem >> 4) * 64;
    int c = tid & 63, rq = tid >> 6;
    for (int i = 0; i < 16; ++i) {
      int r = i * 4 + rq;
      ts[r][c] = W[(size_t)(k0 + r) * HIDDEN + n0 + c];
    }
    __syncthreads();
    for (int i = 0; i < 16; ++i) {
      int n = i * 4 + rq;
      out[(size_t)(n0 + n) * HIDDEN + k0 + c] = f2bf(ts[c][n]);
    }
  } else if (bid < 8968) {
    int i = (bid - 8960) * 256 + tid;
    bkv[i] = (i < HIDDEN) ? bk[i] : bv[i - HIDDEN];
  } else {
    int b = bid - 8968;
    float s = 0.f;
    for (int i = tid; i < SEQ; i += 256) s += mask[b * SEQ + i];
    for (int off = 32; off; off >>= 1) s += __shfl_down(s, off);
    __shared__ float wsum[4];
    if ((tid & 63) == 0) wsum[tid >> 6] = s;
    __syncthreads();
    if (tid == 0) {
      float t = wsum[0] + wsum[1] + wsum[2] + wsum[3];
      norm[b] = rsqrtf(t * (float)HDIM);
    }
  }
}

// ---------------- 256x128 GEMM, BK=32, dbuf, 64 KiB LDS -> 2 blocks/CU ----------------
// C[row][n] = sum_k A[row][k]*Bt[n][k] + bias[n], then * mask[row].
// OUT_MODE 2: bf16 transposed KVt[(n*4+b)*4096+s].
// OUT_MODE 4: FUSED out = ((xWq+bq)*mask) @ kv_head -> f32 row-major out.
// 8 waves: wm=wave>>1 (0..3, 64-row band), wn=wave&1 (0..1, 64-col band).
// K-loop = proven race-free m97 pattern: {STAGE(t+1)->buf (t+1)&1; read frags(t);
// 16 MFMA; vmcnt(0); barrier}. Cross-block co-residency (2/CU) hides the drain.
template <int OUT_MODE>
__global__ __launch_bounds__(512, 4) void gemm256_k(
    const unsigned short* __restrict__ A, const unsigned short* __restrict__ Bt,
    const float* __restrict__ bias, const float* __restrict__ mask,
    const unsigned short* __restrict__ kvt,
    void* __restrict__ C, int nbn) {
  __shared__ unsigned short smem[32768];  // 64 KiB: 2 bufs x (A 256x32 + B 128x32) + epilogue

  const int nwg = gridDim.x;
  const int bid = blockIdx.x;
  const int wg = (bid & 7) * (nwg >> 3) + (bid >> 3);  // XCD swizzle (nwg%8==0)
  const int row0 = (wg / nbn) * 256;
  const int col0 = (wg % nbn) * 128;

  const int tid = threadIdx.x;
  const int wave = tid >> 6;
  const int lane = tid & 63;
  const int wm = wave >> 1;   // 0..3 (64-row band)
  const int wn = wave & 1;    // 0..1 (64-col band)
  const int lr = lane & 15;
  const int hi = lane >> 4;   // 0..3

  // staging: linear LDS dest, inverse-swizzled global source (chunk ^= (row>>1)&3)
  const int srow = tid >> 2;                            // 0..127
  const int sc = ((tid & 3) ^ ((srow >> 1) & 3)) * 8;   // 8-elem chunk, value-proven (R12)
  const unsigned short* sA0 = A + (size_t)(row0 + srow) * HIDDEN + sc;
  const unsigned short* sA1 = A + (size_t)(row0 + 128 + srow) * HIDDEN + sc;
  const unsigned short* sB0 = Bt + (size_t)(col0 + srow) * HIDDEN + sc;

#define STAGE_A(tt) { int dst_ = ((tt) & 1) * 12288 + tid * 8; \
    load_lds16(sA0 + (size_t)(tt) * 32, &smem[dst_]); \
    load_lds16(sA1 + (size_t)(tt) * 32, &smem[dst_ + 4096]); }
#define STAGE_B(tt) { int dst_ = ((tt) & 1) * 12288 + 8192 + tid * 8; \
    load_lds16(sB0 + (size_t)(tt) * 32, &smem[dst_]); }

  // frag read: row ra -> ra*32 + ((hi ^ ((ra>>1)&3))*8); (ra>>1)&3 == (lr>>1)&3
  const int kch = (hi ^ ((lr >> 1) & 3)) * 8;
  const int aoff = (wm * 64 + lr) * 32;           // + rf*512
  const int boff = 8192 + (wn * 64 + lr) * 32;    // + cf*512

  f32x4 acc[4][4];
#pragma unroll
  for (int i = 0; i < 4; ++i)
#pragma unroll
    for (int j = 0; j < 4; ++j) acc[i][j] = (f32x4){0.f, 0.f, 0.f, 0.f};

  // prologue: stage tile 0; drain; barrier
  STAGE_A(0) STAGE_B(0)
  asm volatile("s_waitcnt vmcnt(0)" ::: "memory");
  __builtin_amdgcn_s_barrier();

  for (int t = 0; t < NT; ++t) {
    const int bb = (t & 1) * 12288;
    if (t + 1 < NT) { STAGE_A(t + 1) STAGE_B(t + 1) }
    bf16x8 af[4], bf[4];
#pragma unroll
    for (int rf = 0; rf < 4; ++rf)
      af[rf] = *(const bf16x8*)&smem[bb + aoff + rf * 512 + kch];
#pragma unroll
    for (int cf = 0; cf < 4; ++cf)
      bf[cf] = *(const bf16x8*)&smem[bb + boff + cf * 512 + kch];
    __builtin_amdgcn_s_setprio(1);
#pragma unroll
    for (int rf = 0; rf < 4; ++rf)
#pragma unroll
      for (int cf = 0; cf < 4; ++cf)
        acc[rf][cf] = __builtin_amdgcn_mfma_f32_16x16x32_bf16(af[rf], bf[cf], acc[rf][cf], 0, 0, 0);
    __builtin_amdgcn_s_setprio(0);
    asm volatile("s_waitcnt vmcnt(0)" ::: "memory");
    __builtin_amdgcn_s_barrier();
  }

  // ---- epilogue ----
  float bcol[4];
#pragma unroll
  for (int cf = 0; cf < 4; ++cf)
    bcol[cf] = bias[col0 + wn * 64 + cf * 16 + lr];

  unsigned short* wt = &smem[wave * 4096];  // per-wave 64x64 bf16 (8 KiB)

  if (OUT_MODE == 2) {
    // transposed bf16 store: KVt[(n*4+b)*4096 + s]
    const int b = row0 >> 12;
    const int s0 = (row0 & 4095) + wm * 64;
    unsigned short* KVt = (unsigned short*)C;
#pragma unroll
    for (int rf = 0; rf < 4; ++rf)
#pragma unroll
      for (int j = 0; j < 4; ++j) {
        int r = rf * 16 + hi * 4 + j;  // 0..63
        float mrow = mask[row0 + wm * 64 + r];
#pragma unroll
        for (int cf = 0; cf < 4; ++cf) {
          int c = cf * 16 + lr;
          wt[c * 64 + (r ^ ((c & 7) << 3))] = f2bf((acc[rf][cf][j] + bcol[cf]) * mrow);
        }
      }
    asm volatile("s_waitcnt lgkmcnt(0)" ::: "memory");
#pragma unroll
    for (int i = 0; i < 8; ++i) {
      int flat = i * 64 + lane;
      int c = flat >> 3, rq = flat & 7;
      uint4 vv = *(const uint4*)&wt[c * 64 + ((rq * 8) ^ ((c & 7) << 3))];
      *(uint4*)&KVt[((size_t)(col0 + wn * 64 + c) * 4 + b) * 4096 + s0 + rq * 8] = vv;
    }
    asm volatile("s_waitcnt lgkmcnt(0)" ::: "memory");
  } else {
    // OUT_MODE 4: fused q @ kv_head -> f32 out
    float* Og = (float*)C;
    const int b = row0 >> 12;
    const int bh = b * 16 + (col0 >> 6) + wn;  // this wave's head
    bf16x8 kvf[4][2];
#pragma unroll
    for (int et = 0; et < 4; ++et) {
      kvf[et][0] = *(const bf16x8*)&kvt[(size_t)bh * 4096 + (et * 16 + lr) * 64 + hi * 8];
      kvf[et][1] = *(const bf16x8*)&kvt[(size_t)bh * 4096 + (et * 16 + lr) * 64 + 32 + hi * 8];
    }
    // write whole 64x64 biased/masked q tile to wt (acc consumed)
#pragma unroll
    for (int rf = 0; rf < 4; ++rf)
#pragma unroll
      for (int j = 0; j < 4; ++j) {
        int r = rf * 16 + hi * 4 + j;
        float mrow = mask[row0 + wm * 64 + r];
#pragma unroll
        for (int cf = 0; cf < 4; ++cf) {
          int c = cf * 16 + lr;
          wt[r * 64 + (c ^ ((r & 7) << 3))] = f2bf((acc[rf][cf][j] + bcol[cf]) * mrow);
        }
      }
    asm volatile("s_waitcnt lgkmcnt(0)" ::: "memory");
    const int echunk0 = (hi ^ (lr & 7)) * 8;
    const int echunk1 = ((4 + hi) ^ (lr & 7)) * 8;
#pragma unroll
    for (int g = 0; g < 4; ++g) {
      bf16x8 a0 = *(const bf16x8*)&wt[(g * 16 + lr) * 64 + echunk0];
      bf16x8 a1 = *(const bf16x8*)&wt[(g * 16 + lr) * 64 + echunk1];
#pragma unroll
      for (int et = 0; et < 4; ++et) {
        f32x4 o4 = (f32x4){0.f, 0.f, 0.f, 0.f};
        o4 = __builtin_amdgcn_mfma_f32_16x16x32_bf16(a0, kvf[et][0], o4, 0, 0, 0);
        o4 = __builtin_amdgcn_mfma_f32_16x16x32_bf16(a1, kvf[et][1], o4, 0, 0, 0);
#pragma unroll
        for (int j = 0; j < 4; ++j)
          __builtin_nontemporal_store(o4[j],
              &Og[(size_t)(row0 + wm * 64 + g * 16 + hi * 4 + j) * 1024
                  + col0 + wn * 64 + et * 16 + lr]);
      }
    }
    asm volatile("s_waitcnt lgkmcnt(0)" ::: "memory");
  }
#undef STAGE_A
#undef STAGE_B
}

// ---------------- kv partials via MFMA: part[ch][bh][d][e] = sum_s Kt[d][s]*Vt[e][s] ----
__global__ __launch_bounds__(256) void kvpart2_k(const unsigned short* __restrict__ KVt,
                                                 float* __restrict__ part) {
  const int bh = blockIdx.x, ch = blockIdx.y;
  const int b = bh >> 4, h = bh & 15;
  __shared__ unsigned short tl[32768];  // 4 bufs x (A[64][64] + B[64][64]) = 64 KiB
  const int tid = threadIdx.x;
  const int wave = tid >> 6, lane = tid & 63;
  const int lr = lane & 15, hi = lane >> 4;

  const int r0 = tid >> 3;
  const int cc0 = ((tid & 7) ^ (r0 & 7)) * 8;
  const int r1 = 32 + r0;
  const int cc1 = ((tid & 7) ^ (r1 & 7)) * 8;
  const unsigned short* A0 = KVt + ((size_t)(h * 64 + r0) * 4 + b) * 4096 + ch * 1024 + cc0;
  const unsigned short* A1 = KVt + ((size_t)(h * 64 + r1) * 4 + b) * 4096 + ch * 1024 + cc1;
  const unsigned short* B0 = KVt + ((size_t)(1024 + h * 64 + r0) * 4 + b) * 4096 + ch * 1024 + cc0;
  const unsigned short* B1 = KVt + ((size_t)(1024 + h * 64 + r1) * 4 + b) * 4096 + ch * 1024 + cc1;

#define KSTAGE(tt) { int bb2 = ((tt) & 3) * 8192; \
    load_lds16(A0 + (tt) * 64, &tl[bb2 + tid * 8]); \
    load_lds16(A1 + (tt) * 64, &tl[bb2 + 2048 + tid * 8]); \
    load_lds16(B0 + (tt) * 64, &tl[bb2 + 4096 + tid * 8]); \
    load_lds16(B1 + (tt) * 64, &tl[bb2 + 6144 + tid * 8]); }

  const int ra = wave * 16 + lr;
  const int aoff = ra * 64;
  const int ach0 = (hi ^ (ra & 7)) * 8, ach1 = ((4 + hi) ^ (ra & 7)) * 8;

  f32x4 acc4[4];
#pragma unroll
  for (int nt = 0; nt < 4; ++nt) acc4[nt] = (f32x4){0.f, 0.f, 0.f, 0.f};

  KSTAGE(0) KSTAGE(1)
  asm volatile("s_waitcnt vmcnt(4)" ::: "memory");
  __builtin_amdgcn_s_barrier();
  for (int t = 0; t < 16; ++t) {
    const int bb = (t & 3) * 8192;
    if (t + 2 < 16) KSTAGE(t + 2)
    bf16x8 a0 = *(const bf16x8*)&tl[bb + aoff + ach0];
    bf16x8 a1 = *(const bf16x8*)&tl[bb + aoff + ach1];
    bf16x8 bf0[4], bf1[4];
#pragma unroll
    for (int nt = 0; nt < 4; ++nt) {
      int rb = nt * 16 + lr;
      bf0[nt] = *(const bf16x8*)&tl[bb + 4096 + rb * 64 + ((hi ^ (rb & 7)) * 8)];
      bf1[nt] = *(const bf16x8*)&tl[bb + 4096 + rb * 64 + (((4 + hi) ^ (rb & 7)) * 8)];
    }
#pragma unroll
    for (int nt = 0; nt < 4; ++nt) {
      acc4[nt] = __builtin_amdgcn_mfma_f32_16x16x32_bf16(a0, bf0[nt], acc4[nt], 0, 0, 0);
      acc4[nt] = __builtin_amdgcn_mfma_f32_16x16x32_bf16(a1, bf1[nt], acc4[nt], 0, 0, 0);
    }
    if (t < 14) asm volatile("s_waitcnt vmcnt(4)" ::: "memory");
    else        asm volatile("s_waitcnt vmcnt(0)" ::: "memory");
    __builtin_amdgcn_s_barrier();
  }
  float* dst = part + ((size_t)(ch * 64 + bh)) * 4096;
#pragma unroll
  for (int nt = 0; nt < 4; ++nt)
#pragma unroll
    for (int j = 0; j < 4; ++j)
      dst[(wave * 16 + hi * 4 + j) * 64 + nt * 16 + lr] = acc4[nt][j];
#undef KSTAGE
}

// ---------------- reduce + transpose + norm: kvt[bh][e][d] bf16 ----------------
__global__ void kvreduce_k(const float* __restrict__ part, const float* __restrict__ norm,
                           unsigned short* __restrict__ kvt) {
  int idx4 = (blockIdx.x * 256 + threadIdx.x) * 4;  // [bh][e][d0..d0+3]
  int bh = idx4 >> 12, rem = idx4 & 4095;
  int e = rem >> 6, d0 = rem & 63;
  float s0 = 0.f, s1 = 0.f, s2 = 0.f, s3 = 0.f;
#pragma unroll
  for (int ch = 0; ch < NCH; ++ch) {
    const float* p = part + ((size_t)(ch * 64 + bh)) * 4096 + e;  // [d][e] layout
    s0 += p[(d0 + 0) * 64];
    s1 += p[(d0 + 1) * 64];
    s2 += p[(d0 + 2) * 64];
    s3 += p[(d0 + 3) * 64];
  }
  float nb = norm[bh >> 4];
  ushort4 o;
  o.x = f2bf(s0 * nb); o.y = f2bf(s1 * nb); o.z = f2bf(s2 * nb); o.w = f2bf(s3 * nb);
  *(ushort4*)&kvt[idx4] = o;
}

// ---------------- launch ----------------
extern "C" void kernel_launch(void* const* d_in, const int* in_sizes, int n_in,
                              void* d_out, int out_size, void* d_ws, size_t ws_size,
                              hipStream_t stream) {
  const float* x = (const float*)d_in[0];
  const float* mask = (const float*)d_in[1];
  const float* Wq = (const float*)d_in[2];
  const float* bq = (const float*)d_in[3];
  const float* Wk = (const float*)d_in[4];
  const float* bk = (const float*)d_in[5];
  const float* Wv = (const float*)d_in[6];
  const float* bv = (const float*)d_in[7];
  float* out = (float*)d_out;

  char* w = (char*)d_ws;
  unsigned short* xb = (unsigned short*)w;   w += (size_t)M_TOT * HIDDEN * 2;       // 32 MiB
  unsigned short* Bt = (unsigned short*)w;   w += (size_t)2048 * HIDDEN * 2;        // 4 MiB
  unsigned short* Wqt = (unsigned short*)w;  w += (size_t)HIDDEN * HIDDEN * 2;      // 2 MiB
  unsigned short* KVt = (unsigned short*)w;  w += (size_t)2048 * BATCH * SEQ * 2;   // 64 MiB
  float* part = (float*)w;                   w += (size_t)NCH * 64 * 4096 * 4;      // 4 MiB
  unsigned short* kvt = (unsigned short*)w;  w += (size_t)64 * 4096 * 2;            // 0.5 MiB
  float* bkv = (float*)w;                    w += 2048 * 4;
  float* norm = (float*)w;                   w += 64;

  prep_k<<<dim3(8972), dim3(256), 0, stream>>>(x, xb, Wk, Wv, Wq, Bt, Wqt, bk, bv, bkv, mask, norm);
  // KV projection: M=16384, N=2048, tiles 256x128 -> 64*16 = 1024 blocks
  gemm256_k<2><<<dim3(1024), dim3(512), 0, stream>>>(xb, Bt, bkv, mask, nullptr, (void*)KVt, 16);
  kvpart2_k<<<dim3(64, NCH), dim3(256), 0, stream>>>(KVt, part);
  kvreduce_k<<<dim3(256), dim3(256), 0, stream>>>(part, norm, kvt);
  // Fused Q projection + out = q @ kv_head: M=16384, N=1024 -> 64*8 = 512 blocks
  gemm256_k<4><<<dim3(512), dim3(512), 0, stream>>>(xb, Wqt, bq, mask, kvt, (void*)out, 8);
}